// Round 6
// baseline (235.677 us; speedup 1.0000x reference)
//
#include <hip/hip_runtime.h>
#include <stdint.h>

#define BATCH 64
#define SLEN 512
#define HID 128
#define NHEAD 4
#define DPROJ 512            // HID * NHEAD
#define MTOT (BATCH * SLEN)  // 32768
#define SCALE 0.08838834764831845f
#define LOG2E 1.4426950408889634f

using short8 = __attribute__((ext_vector_type(8))) short;
using f32x4  = __attribute__((ext_vector_type(4))) float;
using u32x4  = __attribute__((ext_vector_type(4))) unsigned int;
using u32x2  = __attribute__((ext_vector_type(2))) unsigned int;
using us4    = __attribute__((ext_vector_type(4))) unsigned short;

__device__ __forceinline__ unsigned short f2bf(float f) {
  unsigned int u = __float_as_uint(f);
  u += 0x7fffu + ((u >> 16) & 1u);   // round-to-nearest-even
  return (unsigned short)(u >> 16);
}

// ---------------------------------------------------------------------------
// Kernel 0: prep — weights only (1024 blocks, ~2 MB).
// ---------------------------------------------------------------------------
__global__ __launch_bounds__(256) void prep_kernel(
    const float* __restrict__ Wq,
    const float* __restrict__ Wk,
    const float* __restrict__ Wv,
    const float* __restrict__ Wo,
    unsigned short* __restrict__ WT,
    unsigned short* __restrict__ WoT)
{
  int idx = blockIdx.x * 256 + threadIdx.x;
  int z = idx >> 16;
  int i = idx & 65535;
  if (z < 3) {
    const float* W = (z == 0) ? Wq : (z == 1) ? Wk : Wv;
    float scale = (z == 0) ? (SCALE * LOG2E) : 1.0f;  // exp2 form
    int k = i >> 9;
    int n = i & 511;
    WT[(size_t)z * 65536 + (size_t)n * 128 + k] = f2bf(W[i] * scale);
  } else {
    int k = i >> 7;
    int n = i & 127;
    WoT[(size_t)n * 512 + k] = f2bf(Wo[i]);
  }
}

// ---------------------------------------------------------------------------
// Kernel 1: QKV projection + mask bit-pack — R16.
// R15 put mask blocks at bid>=1024 -> dispatcher ran them as a ~30us serial
// TAIL after GEMM retired (qkv 76us, HBM 28%, all pipes idle). R16
// interleaves them 1:1: grid 2048, even bid = GEMM block (g=bid>>1, same
// nt/mt mapping -> L2 enc reuse intact), odd bid = mask chunk (16 units).
// Mask work is pure BW (~67 MB) and now co-resident with GEMM blocks for
// the whole dispatch -> overlaps MFMA/LDS phases instead of trailing them.
// ---------------------------------------------------------------------------
__global__ __launch_bounds__(256) void qkv_kernel(
    const float* __restrict__ enc,            // (M,128) fp32
    const int* __restrict__ mask,             // (B,1,S,S) int32
    const unsigned short* __restrict__ WT,    // (3,512,128) bf16 n-major
    unsigned short* __restrict__ Qh,
    unsigned short* __restrict__ Kh,
    unsigned short* __restrict__ Vt,
    unsigned int* __restrict__ mbits)
{
  const int bid = blockIdx.x;
  const int t = threadIdx.x;

  if (bid & 1) {
    // ---- mask bit-pack: 1024 odd blocks x 4 waves x 16 units of 256 ints --
    const int l = t & 63;
    const int wv = t >> 6;
    #pragma unroll 4
    for (int it = 0; it < 16; ++it) {
      size_t vb = (size_t)(bid >> 1) * 16 + it;
      size_t wavebase = vb * 1024 + (size_t)wv * 256;
      unsigned long long b0 = __ballot(mask[wavebase + 0 * 64 + l] != 0);
      unsigned long long b1 = __ballot(mask[wavebase + 1 * 64 + l] != 0);
      unsigned long long b2 = __ballot(mask[wavebase + 2 * 64 + l] != 0);
      unsigned long long b3 = __ballot(mask[wavebase + 3 * 64 + l] != 0);
      if (l < 4) {
        unsigned long long v = (l & 2) ? ((l & 1) ? b3 : b2) : ((l & 1) ? b1 : b0);
        *(unsigned long long*)(mbits + (wavebase >> 5) + l * 2) = v;
      }
    }
    return;
  }

  const int g = bid >> 1;    // 0..1023
  const int nt = g & 3;      // head (consecutive g share mt -> L2 reuse of A)
  const int mt = g >> 2;     // 0..255
  const int lane = t & 63;
  const int w = t >> 6;
  const int quad = lane >> 4;
  const int l16 = lane & 15;

  __shared__ __align__(16) unsigned short Ald[128 * 136];     // 34816 B
  __shared__ __align__(16) unsigned short Bld[2][128 * 72];   // 36864 B

  const int m0 = mt * 128, n0 = nt * 128;
  const int wm = (w >> 1) * 64, wn = (w & 1) * 64;

  const int b_row = t >> 3, b_col = (t & 7) << 3;  // B-stage: +32 rows per i

  // prologue: A (fp32 -> bf16 cast) -> Ald; B(s=0) -> Bld[0]; B(s=1) -> regs
  {
    u32x4 breg0[4];
    #pragma unroll
    for (int i = 0; i < 4; ++i)
      breg0[i] = *(const u32x4*)(WT + (size_t)(n0 + b_row + i * 32) * HID + b_col);
    #pragma unroll
    for (int i = 0; i < 8; ++i) {
      int idx = i * 256 + t;
      int row = idx >> 4;
      int col = (idx & 15) << 3;
      const float* src = enc + (size_t)(m0 + row) * HID + col;
      f32x4 a0 = *(const f32x4*)(src);
      f32x4 a1 = *(const f32x4*)(src + 4);
      short8 v;
      #pragma unroll
      for (int j = 0; j < 4; ++j) v[j] = (short)f2bf(a0[j]);
      #pragma unroll
      for (int j = 0; j < 4; ++j) v[4 + j] = (short)f2bf(a1[j]);
      *(short8*)(Ald + row * 136 + col) = v;
    }
    #pragma unroll
    for (int i = 0; i < 4; ++i)
      *(u32x4*)(Bld[0] + (b_row + i * 32) * 72 + b_col) = breg0[i];
  }
  u32x4 breg[4];
  #pragma unroll
  for (int i = 0; i < 4; ++i)   // s=1: z=0, kc=1
    breg[i] = *(const u32x4*)(WT + (size_t)(n0 + b_row + i * 32) * HID + 64 + b_col);
  asm volatile("s_waitcnt lgkmcnt(0)" ::: "memory");
  __builtin_amdgcn_s_barrier();

  f32x4 acc[4][4];
  #pragma unroll
  for (int s = 0; s < 6; ++s) {
    const int z = s >> 1, kc = s & 1, p = s & 1;
    if (kc == 0) {
      #pragma unroll
      for (int mi = 0; mi < 4; ++mi)
        #pragma unroll
        for (int ni = 0; ni < 4; ++ni)
          acc[mi][ni] = f32x4{0.f, 0.f, 0.f, 0.f};
    }

    const unsigned short* Br = Bld[p];
    #pragma unroll
    for (int kk = 0; kk < 2; ++kk) {
      short8 a[4], bb[4];
      #pragma unroll
      for (int mi = 0; mi < 4; ++mi)
        a[mi] = *(const short8*)(Ald + (wm + mi * 16 + l16) * 136 + kc * 64 + kk * 32 + quad * 8);
      #pragma unroll
      for (int ni = 0; ni < 4; ++ni)
        bb[ni] = *(const short8*)(Br + (wn + ni * 16 + l16) * 72 + kk * 32 + quad * 8);
      if (z < 2) {
        #pragma unroll
        for (int mi = 0; mi < 4; ++mi)
          #pragma unroll
          for (int ni = 0; ni < 4; ++ni)
            acc[mi][ni] = __builtin_amdgcn_mfma_f32_16x16x32_bf16(bb[ni], a[mi], acc[mi][ni], 0, 0, 0);
      } else {
        #pragma unroll
        for (int mi = 0; mi < 4; ++mi)
          #pragma unroll
          for (int ni = 0; ni < 4; ++ni)
            acc[mi][ni] = __builtin_amdgcn_mfma_f32_16x16x32_bf16(a[mi], bb[ni], acc[mi][ni], 0, 0, 0);
      }
    }

    if (s < 5) {
      // write prefetched B(s+1) into the idle buffer; issue loads for s+2
      unsigned short* Bw2 = Bld[p ^ 1];
      #pragma unroll
      for (int i = 0; i < 4; ++i)
        *(u32x4*)(Bw2 + (b_row + i * 32) * 72 + b_col) = breg[i];
      if (s < 4) {
        const int s2 = s + 2;
        const unsigned short* Wz = WT + (size_t)(s2 >> 1) * DPROJ * HID;
        #pragma unroll
        for (int i = 0; i < 4; ++i)
          breg[i] = *(const u32x4*)(Wz + (size_t)(n0 + b_row + i * 32) * HID + (s2 & 1) * 64 + b_col);
      }
      asm volatile("s_waitcnt lgkmcnt(0)" ::: "memory");
      __builtin_amdgcn_s_barrier();
    }

    if (kc == 1) {
      if (z < 2) {
        // D[n][m]: col(l16)=m-within-16, row(quad*4+r)=d-within-16
        unsigned short* outz = ((z == 0) ? Qh : Kh) + (size_t)nt * MTOT * HID;
        #pragma unroll
        for (int mi = 0; mi < 4; ++mi)
          #pragma unroll
          for (int ni = 0; ni < 4; ++ni) {
            int m = m0 + wm + mi * 16 + l16;
            int dbase = wn + ni * 16 + quad * 4;
            us4 pk;
            #pragma unroll
            for (int r = 0; r < 4; ++r) pk[r] = f2bf(acc[mi][ni][r]);
            *(us4*)(outz + (size_t)m * HID + dbase) = pk;
          }
      } else {
        // D[m][n]: reg axis = s (4 consecutive) -> Vt[(nt*B+b)*128 + d][s]
        #pragma unroll
        for (int mi = 0; mi < 4; ++mi)
          #pragma unroll
          for (int ni = 0; ni < 4; ++ni) {
            int row0 = m0 + wm + mi * 16 + quad * 4;
            int b = row0 >> 9, sres = row0 & 511;
            int d = wn + ni * 16 + l16;
            us4 pk;
            #pragma unroll
            for (int r = 0; r < 4; ++r) pk[r] = f2bf(acc[mi][ni][r]);
            *(us4*)(Vt + ((size_t)(nt * BATCH + b) * HID + d) * SLEN + sres) = pk;
          }
      }
    }
  }
}

// ---------------------------------------------------------------------------
// Kernel 2: flash attention — R13 (frozen; measured 55.0us, VGPR 60).
// ---------------------------------------------------------------------------
__global__ __launch_bounds__(512, 4) void attn_kernel(
    const unsigned short* __restrict__ Qh,   // (NH, M, 128)
    const unsigned short* __restrict__ Kh,   // (NH, M, 128)
    const unsigned short* __restrict__ Vt,   // (NH, B, 128, S)
    const unsigned int* __restrict__ mbits,  // (B, S, 16)
    unsigned short* __restrict__ ctx)        // (M, 512)
{
  const int lin = blockIdx.x;              // 0..1023
  const int work = (lin & 7) * 128 + (lin >> 3);
  const int qt = work & 3;
  const int h  = (work >> 2) & 3;
  const int b  = work >> 4;

  const int t = threadIdx.x;
  const int lane = t & 63;
  const int w = t >> 6;                    // 0..7
  const int quad = lane >> 4;
  const int l16 = lane & 15;

  __shared__ __align__(16) unsigned short Kld[2][64 * 136];   // 34816 B
  __shared__ __align__(16) unsigned short Vtld[2][128 * 72];  // 36864 B

  const int q0 = qt * 128;
  const size_t rowbase = (size_t)b * SLEN;
  const unsigned short* kbase0 = Kh + ((size_t)h * MTOT + rowbase) * HID;
  const unsigned short* vbase  = Vt + (size_t)(h * BATCH + b) * HID * SLEN;
  const unsigned int* mrow = mbits + (size_t)b * SLEN * 16;

  const int k_key = t >> 4, k_col = (t & 15) << 3;   // +32 keys at i=1
  const int v_d   = t >> 3, v_cc  = (t & 7) << 3;    // +64 d at i=1

  short8 qa[4];
  {
    const unsigned short* qbase =
        Qh + ((size_t)h * MTOT + rowbase + q0 + w * 16 + l16) * HID + quad * 8;
    #pragma unroll
    for (int kk = 0; kk < 4; ++kk)
      qa[kk] = *(const short8*)(qbase + kk * 32);
  }

  short8 ones;
  #pragma unroll
  for (int j = 0; j < 8; ++j) ones[j] = (short)0x3F80;  // bf16 1.0

  f32x4 oc[8], oc9;
  #pragma unroll
  for (int nd = 0; nd < 8; ++nd) oc[nd] = f32x4{0.f, 0.f, 0.f, 0.f};
  oc9 = f32x4{0.f, 0.f, 0.f, 0.f};

  // per-lane q-row is fixed: one mask base
  const unsigned int* mq = mrow + (size_t)(q0 + w * 16 + l16) * 16;

  // prologue: load chunk 0 -> regs -> buf0; load chunk 1 -> regs; barrier
  u32x4 kreg[2], vreg[2];
  #pragma unroll
  for (int i = 0; i < 2; ++i) {
    kreg[i] = *(const u32x4*)(kbase0 + (size_t)(k_key + i * 32) * HID + k_col);
    vreg[i] = *(const u32x4*)(vbase + (size_t)(v_d + i * 64) * SLEN + v_cc);
  }
  #pragma unroll
  for (int i = 0; i < 2; ++i) {
    *(u32x4*)(Kld[0] + (k_key + i * 32) * 136 + k_col) = kreg[i];
    *(u32x4*)(Vtld[0] + (v_d + i * 64) * 72 + v_cc) = vreg[i];
  }
  #pragma unroll
  for (int i = 0; i < 2; ++i) {
    kreg[i] = *(const u32x4*)(kbase0 + (size_t)(64 + k_key + i * 32) * HID + k_col);
    vreg[i] = *(const u32x4*)(vbase + (size_t)(v_d + i * 64) * SLEN + 64 + v_cc);
  }
  asm volatile("s_waitcnt lgkmcnt(0)" ::: "memory");
  __builtin_amdgcn_s_barrier();

  for (int c0 = 0; c0 < SLEN; c0 += 64) {
    const int p = (c0 >> 6) & 1;
    const unsigned short* Kr = Kld[p];
    const unsigned short* Vr = Vtld[p];

    // stage chunk c+1 (held in regs) into the other buffer; then issue
    // global loads for chunk c+2 (land during compute of c and c+1)
    if (c0 + 64 < SLEN) {
      unsigned short* Kw = Kld[p ^ 1];
      unsigned short* Vw = Vtld[p ^ 1];
      #pragma unroll
      for (int i = 0; i < 2; ++i) {
        *(u32x4*)(Kw + (k_key + i * 32) * 136 + k_col) = kreg[i];
        *(u32x4*)(Vw + (v_d + i * 64) * 72 + v_cc) = vreg[i];
      }
      if (c0 + 128 < SLEN) {
        #pragma unroll
        for (int i = 0; i < 2; ++i) {
          kreg[i] = *(const u32x4*)(kbase0 + (size_t)(c0 + 128 + k_key + i * 32) * HID + k_col);
          vreg[i] = *(const u32x4*)(vbase + (size_t)(v_d + i * 64) * SLEN + c0 + 128 + v_cc);
        }
      }
    }

    // mask bits: 64 keys for this lane's q-row (used after QK^T)
    u32x2 mw = *(const u32x2*)(mq + (c0 >> 5));

    // S^T = (Q K^T)^T via swapped operands: lane l16 = q, regs = keys
    f32x4 sc[4];
    #pragma unroll
    for (int ni = 0; ni < 4; ++ni) sc[ni] = f32x4{0.f, 0.f, 0.f, 0.f};
    __builtin_amdgcn_s_setprio(1);
    #pragma unroll
    for (int kk = 0; kk < 4; ++kk) {
      #pragma unroll
      for (int ni = 0; ni < 4; ++ni) {
        short8 bb = *(const short8*)(Kr + (ni * 16 + l16) * 136 + kk * 32 + quad * 8);
        sc[ni] = __builtin_amdgcn_mfma_f32_16x16x32_bf16(bb, qa[kk], sc[ni], 0, 0, 0);
      }
    }
    __builtin_amdgcn_s_setprio(0);

    // p = mask ? exp2(s) : 0, packed to bf16 pairs in-register
    unsigned int pk[4][2];
    #pragma unroll
    for (int ni = 0; ni < 4; ++ni) {
      unsigned wsel = (ni < 2) ? mw[0] : mw[1];
      float pp[4];
      #pragma unroll
      for (int r = 0; r < 4; ++r) {
        int bit = (ni & 1) * 16 + quad * 4 + r;
        float e = __builtin_amdgcn_exp2f(sc[ni][r]);   // raw v_exp_f32
        pp[r] = ((wsel >> bit) & 1u) ? e : 0.f;
      }
      asm("v_cvt_pk_bf16_f32 %0, %1, %2" : "=v"(pk[ni][0]) : "v"(pp[0]), "v"(pp[1]));
      asm("v_cvt_pk_bf16_f32 %0, %1, %2" : "=v"(pk[ni][1]) : "v"(pp[2]), "v"(pp[3]));
    }

    // O += P @ V ; rowsum += P @ 1 ; P A-frags assembled via permlane swaps
    #pragma unroll
    for (int kb = 0; kb < 2; ++kb) {
      unsigned int c0w = pk[kb * 2][0], c2w = pk[kb * 2 + 1][0];
      asm("v_permlane32_swap_b32 %0, %1" : "+v"(c0w), "+v"(c2w));
      asm("v_permlane16_swap_b32 %0, %1" : "+v"(c0w), "+v"(c2w));
      unsigned int c1w = pk[kb * 2][1], c3w = pk[kb * 2 + 1][1];
      asm("v_permlane32_swap_b32 %0, %1" : "+v"(c1w), "+v"(c3w));
      asm("v_permlane16_swap_b32 %0, %1" : "+v"(c1w), "+v"(c3w));
      short8 a = __builtin_bit_cast(short8, u32x4{c0w, c1w, c2w, c3w});
      __builtin_amdgcn_s_setprio(1);
      #pragma unroll
      for (int nd = 0; nd < 8; ++nd) {
        short8 bv = *(const short8*)(Vr + (nd * 16 + l16) * 72 + kb * 32 + quad * 8);
        oc[nd] = __builtin_amdgcn_mfma_f32_16x16x32_bf16(a, bv, oc[nd], 0, 0, 0);
      }
      oc9 = __builtin_amdgcn_mfma_f32_16x16x32_bf16(a, ones, oc9, 0, 0, 0);
      __builtin_amdgcn_s_setprio(0);
    }

    // one barrier per chunk: own LDS writes visible, then all waves align.
    // vmcnt NOT drained -> c+2 loads stay in flight across the barrier.
    if (c0 + 64 < SLEN) {
      asm volatile("s_waitcnt lgkmcnt(0)" ::: "memory");
      __builtin_amdgcn_s_barrier();
    }
  }

  // D[q][d] epilogue: rcp once per row, multiply
  float rcp[4];
  #pragma unroll
  for (int r = 0; r < 4; ++r) rcp[r] = __builtin_amdgcn_rcpf(oc9[r]);
  #pragma unroll
  for (int nd = 0; nd < 8; ++nd)
    #pragma unroll
    for (int r = 0; r < 4; ++r) {
      float val = oc[nd][r] * rcp[r];
      int row = q0 + w * 16 + quad * 4 + r;
      int col = h * HID + nd * 16 + l16;
      ctx[(rowbase + row) * DPROJ + col] = f2bf(val);
    }
}

// ---------------------------------------------------------------------------
// Kernel 3: output projection + residual + LayerNorm — R14 (frozen).
// ---------------------------------------------------------------------------
__global__ __launch_bounds__(256, 2) void oproj_ln_kernel(
    const unsigned short* __restrict__ ctx,   // (M,512) bf16
    const unsigned short* __restrict__ WoT,   // (128,512) bf16 n-major
    const float* __restrict__ enc,            // (M,128) fp32
    const float* __restrict__ gamma,
    const float* __restrict__ beta,
    float* __restrict__ out)                  // (M,128) fp32
{
  const int m0 = blockIdx.x * 64;
  const int t = threadIdx.x;
  const int lane = t & 63;
  const int w = t >> 6;
  const int quad = lane >> 4;
  const int l16 = lane & 15;

  __shared__ __align__(16) unsigned short Actx[2][64 * 72];   // 18432 B
  __shared__ __align__(16) unsigned short Bw[2][128 * 72];    // 36864 B

  const int a_row = t >> 3, a_col = (t & 7) << 3;   // +32 rows at i=1 (64 rows)
  const int b_row = t >> 3, b_col = (t & 7) << 3;   // +32 rows per i (128 rows)

  f32x4 acc[8];
  #pragma unroll
  for (int ni = 0; ni < 8; ++ni) acc[ni] = f32x4{0.f, 0.f, 0.f, 0.f};

  // prologue: (kc=0) -> regs -> buf0; (kc=1) -> regs; barrier
  u32x4 areg[2], breg[4];
  #pragma unroll
  for (int i = 0; i < 2; ++i)
    areg[i] = *(const u32x4*)(ctx + (size_t)(m0 + a_row + i * 32) * DPROJ + a_col);
  #pragma unroll
  for (int i = 0; i < 4; ++i)
    breg[i] = *(const u32x4*)(WoT + (size_t)(b_row + i * 32) * DPROJ + b_col);
  #pragma unroll
  for (int i = 0; i < 2; ++i)
    *(u32x4*)(Actx[0] + (a_row + i * 32) * 72 + a_col) = areg[i];
  #pragma unroll
  for (int i = 0; i < 4; ++i)
    *(u32x4*)(Bw[0] + (b_row + i * 32) * 72 + b_col) = breg[i];
  #pragma unroll
  for (int i = 0; i < 2; ++i)
    areg[i] = *(const u32x4*)(ctx + (size_t)(m0 + a_row + i * 32) * DPROJ + 64 + a_col);
  #pragma unroll
  for (int i = 0; i < 4; ++i)
    breg[i] = *(const u32x4*)(WoT + (size_t)(b_row + i * 32) * DPROJ + 64 + b_col);
  asm volatile("s_waitcnt lgkmcnt(0)" ::: "memory");
  __builtin_amdgcn_s_barrier();

  #pragma unroll
  for (int it = 0; it < 8; ++it) {
    const int p = it & 1;
    const unsigned short* Ar = Actx[p];
    const unsigned short* Br = Bw[p];
    #pragma unroll
    for (int kk = 0; kk < 2; ++kk) {
      short8 a = *(const short8*)(Ar + (w * 16 + l16) * 72 + kk * 32 + quad * 8);
      #pragma unroll
      for (int ni = 0; ni < 8; ++ni) {
        short8 bb = *(const short8*)(Br + (ni * 16 + l16) * 72 + kk * 32 + quad * 8);
        acc[ni] = __builtin_amdgcn_mfma_f32_16x16x32_bf16(a, bb, acc[ni], 0, 0, 0);
      }
    }
    if (it < 7) {
      unsigned short* Aw2 = Actx[p ^ 1];
      unsigned short* Bw2 = Bw[p ^ 1];
      #pragma unroll
      for (int i = 0; i < 2; ++i)
        *(u32x4*)(Aw2 + (a_row + i * 32) * 72 + a_col) = areg[i];
      #pragma unroll
      for (int i = 0; i < 4; ++i)
        *(u32x4*)(Bw2 + (b_row + i * 32) * 72 + b_col) = breg[i];
      if (it < 6) {
        const int kc2 = (it + 2) * 64;
        #pragma unroll
        for (int i = 0; i < 2; ++i)
          areg[i] = *(const u32x4*)(ctx + (size_t)(m0 + a_row + i * 32) * DPROJ + kc2 + a_col);
        #pragma unroll
        for (int i = 0; i < 4; ++i)
          breg[i] = *(const u32x4*)(WoT + (size_t)(b_row + i * 32) * DPROJ + kc2 + b_col);
      }
      asm volatile("s_waitcnt lgkmcnt(0)" ::: "memory");
      __builtin_amdgcn_s_barrier();
    }
  }

  float g[8], be[8];
  #pragma unroll
  for (int ni = 0; ni < 8; ++ni) {
    g[ni] = gamma[ni * 16 + l16];
    be[ni] = beta[ni * 16 + l16];
  }

  float val[8][4];
  #pragma unroll
  for (int r = 0; r < 4; ++r) {
    int m = m0 + w * 16 + quad * 4 + r;
    const float* erow = enc + (size_t)m * HID;
    float s = 0.f, s2 = 0.f;
    #pragma unroll
    for (int ni = 0; ni < 8; ++ni) {
      float v = acc[ni][r] + erow[ni * 16 + l16];
      val[ni][r] = v;
      s += v;
      s2 += v * v;
    }
    #pragma unroll
    for (int off = 1; off < 16; off <<= 1) {
      s  += __shfl_xor(s, off, 64);
      s2 += __shfl_xor(s2, off, 64);
    }
    float mean = s * (1.f / 128.f);
    float var = s2 * (1.f / 128.f) - mean * mean;
    float rstd = rsqrtf(var + 1e-6f);
    float* orow = out + (size_t)m * HID;
    #pragma unroll
    for (int ni = 0; ni < 8; ++ni)
      orow[ni * 16 + l16] = g[ni] * (val[ni][r] - mean) * rstd + be[ni];
  }
}

// ---------------------------------------------------------------------------
// ws layout (elements):
//   WT   : 3*512*128 shorts        WoT : 128*512 shorts
//   Qh   : 4*M*128 shorts          Kh  : 4*M*128 shorts
//   Vt   : 4*64*128*512 shorts     ctx : M*512 shorts
//   mbits: 64*512*16 u32
// ---------------------------------------------------------------------------
extern "C" void kernel_launch(void* const* d_in, const int* in_sizes, int n_in,
                              void* d_out, int out_size, void* d_ws, size_t ws_size,
                              hipStream_t stream) {
  const float* enc   = (const float*)d_in[0];
  const int*   mask  = (const int*)d_in[1];
  const float* Wq    = (const float*)d_in[2];
  const float* Wk    = (const float*)d_in[3];
  const float* Wv    = (const float*)d_in[4];
  const float* Wo    = (const float*)d_in[5];
  const float* gamma = (const float*)d_in[6];
  const float* beta  = (const float*)d_in[7];
  float* out = (float*)d_out;

  unsigned short* WT  = (unsigned short*)d_ws;
  unsigned short* WoT = WT + (size_t)3 * DPROJ * HID;
  unsigned short* Qh  = WoT + (size_t)HID * DPROJ;
  unsigned short* Kh  = Qh + (size_t)NHEAD * MTOT * HID;
  unsigned short* Vt  = Kh + (size_t)NHEAD * MTOT * HID;
  unsigned short* ctx = Vt + (size_t)NHEAD * MTOT * HID;
  unsigned int* mbits = (unsigned int*)(ctx + (size_t)MTOT * DPROJ);

  prep_kernel<<<1024, 256, 0, stream>>>(Wq, Wk, Wv, Wo, WT, WoT);
  qkv_kernel<<<2048, 256, 0, stream>>>(enc, mask, WT, Qh, Kh, Vt, mbits);
  attn_kernel<<<1024, 512, 0, stream>>>(Qh, Kh, Vt, mbits, ctx);
  oproj_ln_kernel<<<MTOT / 64, 256, 0, stream>>>(ctx, WoT, enc, gamma, beta, out);
}

// Round 7
// 225.735 us; speedup vs baseline: 1.0440x; 1.0440x over previous
//
#include <hip/hip_runtime.h>
#include <stdint.h>

#define BATCH 64
#define SLEN 512
#define HID 128
#define NHEAD 4
#define DPROJ 512            // HID * NHEAD
#define MTOT (BATCH * SLEN)  // 32768
#define SCALE 0.08838834764831845f
#define LOG2E 1.4426950408889634f

using short8 = __attribute__((ext_vector_type(8))) short;
using f32x4  = __attribute__((ext_vector_type(4))) float;
using u32x4  = __attribute__((ext_vector_type(4))) unsigned int;
using u32x2  = __attribute__((ext_vector_type(2))) unsigned int;
using us4    = __attribute__((ext_vector_type(4))) unsigned short;

__device__ __forceinline__ unsigned short f2bf(float f) {
  unsigned int u = __float_as_uint(f);
  u += 0x7fffu + ((u >> 16) & 1u);   // round-to-nearest-even
  return (unsigned short)(u >> 16);
}

// ---------------------------------------------------------------------------
// Kernel 0: prep — R17. Blocks 0..1023: weight cast+transpose (~2 MB).
// Blocks 1024..2047: mask bit-pack, VECTORIZED: 16 B/lane int4 loads (wave =
// one 256-int tile, fully coalesced), per-lane nibble, 3-step shfl_xor pack.
// Output format bit-identical to the ballot version -> attn untouched.
// (R6 lesson: mask-pack must be a separate dispatch from the GEMM — both
// interleave and tail placements inside qkv regressed.)
// ---------------------------------------------------------------------------
__global__ __launch_bounds__(256) void prep_kernel(
    const float* __restrict__ Wq,
    const float* __restrict__ Wk,
    const float* __restrict__ Wv,
    const float* __restrict__ Wo,
    const int* __restrict__ mask,
    unsigned short* __restrict__ WT,
    unsigned short* __restrict__ WoT,
    unsigned int* __restrict__ mbits)
{
  if (blockIdx.x < 1024) {
    int idx = blockIdx.x * 256 + threadIdx.x;
    int z = idx >> 16;
    int i = idx & 65535;
    if (z < 3) {
      const float* W = (z == 0) ? Wq : (z == 1) ? Wk : Wv;
      float scale = (z == 0) ? (SCALE * LOG2E) : 1.0f;  // exp2 form
      int k = i >> 9;
      int n = i & 511;
      WT[(size_t)z * 65536 + (size_t)n * 128 + k] = f2bf(W[i] * scale);
    } else {
      int k = i >> 7;
      int n = i & 127;
      WoT[(size_t)n * 512 + k] = f2bf(Wo[i]);
    }
  } else {
    // mask -> bitmask: 1024 blocks x 4 waves x 16 tiles of 256 ints.
    const int l = threadIdx.x & 63;
    const int wv = threadIdx.x >> 6;
    const int m = blockIdx.x - 1024;
    #pragma unroll 4
    for (int it = 0; it < 16; ++it) {
      size_t tile = (size_t)m * 64 + (size_t)wv * 16 + it;
      u32x4 v = *(const u32x4*)(mask + tile * 256 + l * 4);
      unsigned nib = (v[0] ? 1u : 0u) | (v[1] ? 2u : 0u) |
                     (v[2] ? 4u : 0u) | (v[3] ? 8u : 0u);
      unsigned a  = nib | ((unsigned)__shfl_xor((int)nib, 1, 64) << 4);
      unsigned b2 = a   | ((unsigned)__shfl_xor((int)a,   2, 64) << 8);
      unsigned c  = b2  | ((unsigned)__shfl_xor((int)b2,  4, 64) << 16);
      if ((l & 7) == 0) mbits[tile * 8 + (l >> 3)] = c;
    }
  }
}

// ---------------------------------------------------------------------------
// Kernel 1: QKV projection — R17: pure GEMM again (grid 1024; R6 showed
// mask co-residency hurts). R15's in-register fp32->bf16 A-cast kept (no
// encb round-trip). Pipelined B: double-buffered LDS, reg prefetch, single
// lgkm-only barrier per stage, vmcnt never drained.
// ---------------------------------------------------------------------------
__global__ __launch_bounds__(256) void qkv_kernel(
    const float* __restrict__ enc,            // (M,128) fp32
    const unsigned short* __restrict__ WT,    // (3,512,128) bf16 n-major
    unsigned short* __restrict__ Qh,
    unsigned short* __restrict__ Kh,
    unsigned short* __restrict__ Vt)
{
  const int g = blockIdx.x;  // 0..1023
  const int nt = g & 3;      // head (consecutive g share mt -> L2 reuse of A)
  const int mt = g >> 2;     // 0..255
  const int t = threadIdx.x;
  const int lane = t & 63;
  const int w = t >> 6;
  const int quad = lane >> 4;
  const int l16 = lane & 15;

  __shared__ __align__(16) unsigned short Ald[128 * 136];     // 34816 B
  __shared__ __align__(16) unsigned short Bld[2][128 * 72];   // 36864 B

  const int m0 = mt * 128, n0 = nt * 128;
  const int wm = (w >> 1) * 64, wn = (w & 1) * 64;

  const int b_row = t >> 3, b_col = (t & 7) << 3;  // B-stage: +32 rows per i

  // prologue: A (fp32 -> bf16 cast) -> Ald; B(s=0) -> Bld[0]; B(s=1) -> regs
  {
    u32x4 breg0[4];
    #pragma unroll
    for (int i = 0; i < 4; ++i)
      breg0[i] = *(const u32x4*)(WT + (size_t)(n0 + b_row + i * 32) * HID + b_col);
    #pragma unroll
    for (int i = 0; i < 8; ++i) {
      int idx = i * 256 + t;
      int row = idx >> 4;
      int col = (idx & 15) << 3;
      const float* src = enc + (size_t)(m0 + row) * HID + col;
      f32x4 a0 = *(const f32x4*)(src);
      f32x4 a1 = *(const f32x4*)(src + 4);
      short8 v;
      #pragma unroll
      for (int j = 0; j < 4; ++j) v[j] = (short)f2bf(a0[j]);
      #pragma unroll
      for (int j = 0; j < 4; ++j) v[4 + j] = (short)f2bf(a1[j]);
      *(short8*)(Ald + row * 136 + col) = v;
    }
    #pragma unroll
    for (int i = 0; i < 4; ++i)
      *(u32x4*)(Bld[0] + (b_row + i * 32) * 72 + b_col) = breg0[i];
  }
  u32x4 breg[4];
  #pragma unroll
  for (int i = 0; i < 4; ++i)   // s=1: z=0, kc=1
    breg[i] = *(const u32x4*)(WT + (size_t)(n0 + b_row + i * 32) * HID + 64 + b_col);
  asm volatile("s_waitcnt lgkmcnt(0)" ::: "memory");
  __builtin_amdgcn_s_barrier();

  f32x4 acc[4][4];
  #pragma unroll
  for (int s = 0; s < 6; ++s) {
    const int z = s >> 1, kc = s & 1, p = s & 1;
    if (kc == 0) {
      #pragma unroll
      for (int mi = 0; mi < 4; ++mi)
        #pragma unroll
        for (int ni = 0; ni < 4; ++ni)
          acc[mi][ni] = f32x4{0.f, 0.f, 0.f, 0.f};
    }

    const unsigned short* Br = Bld[p];
    #pragma unroll
    for (int kk = 0; kk < 2; ++kk) {
      short8 a[4], bb[4];
      #pragma unroll
      for (int mi = 0; mi < 4; ++mi)
        a[mi] = *(const short8*)(Ald + (wm + mi * 16 + l16) * 136 + kc * 64 + kk * 32 + quad * 8);
      #pragma unroll
      for (int ni = 0; ni < 4; ++ni)
        bb[ni] = *(const short8*)(Br + (wn + ni * 16 + l16) * 72 + kk * 32 + quad * 8);
      if (z < 2) {
        #pragma unroll
        for (int mi = 0; mi < 4; ++mi)
          #pragma unroll
          for (int ni = 0; ni < 4; ++ni)
            acc[mi][ni] = __builtin_amdgcn_mfma_f32_16x16x32_bf16(bb[ni], a[mi], acc[mi][ni], 0, 0, 0);
      } else {
        #pragma unroll
        for (int mi = 0; mi < 4; ++mi)
          #pragma unroll
          for (int ni = 0; ni < 4; ++ni)
            acc[mi][ni] = __builtin_amdgcn_mfma_f32_16x16x32_bf16(a[mi], bb[ni], acc[mi][ni], 0, 0, 0);
      }
    }

    if (s < 5) {
      // write prefetched B(s+1) into the idle buffer; issue loads for s+2
      unsigned short* Bw2 = Bld[p ^ 1];
      #pragma unroll
      for (int i = 0; i < 4; ++i)
        *(u32x4*)(Bw2 + (b_row + i * 32) * 72 + b_col) = breg[i];
      if (s < 4) {
        const int s2 = s + 2;
        const unsigned short* Wz = WT + (size_t)(s2 >> 1) * DPROJ * HID;
        #pragma unroll
        for (int i = 0; i < 4; ++i)
          breg[i] = *(const u32x4*)(Wz + (size_t)(n0 + b_row + i * 32) * HID + (s2 & 1) * 64 + b_col);
      }
      asm volatile("s_waitcnt lgkmcnt(0)" ::: "memory");
      __builtin_amdgcn_s_barrier();
    }

    if (kc == 1) {
      if (z < 2) {
        // D[n][m]: col(l16)=m-within-16, row(quad*4+r)=d-within-16
        unsigned short* outz = ((z == 0) ? Qh : Kh) + (size_t)nt * MTOT * HID;
        #pragma unroll
        for (int mi = 0; mi < 4; ++mi)
          #pragma unroll
          for (int ni = 0; ni < 4; ++ni) {
            int m = m0 + wm + mi * 16 + l16;
            int dbase = wn + ni * 16 + quad * 4;
            us4 pk;
            #pragma unroll
            for (int r = 0; r < 4; ++r) pk[r] = f2bf(acc[mi][ni][r]);
            *(us4*)(outz + (size_t)m * HID + dbase) = pk;
          }
      } else {
        // D[m][n]: reg axis = s (4 consecutive) -> Vt[(nt*B+b)*128 + d][s]
        #pragma unroll
        for (int mi = 0; mi < 4; ++mi)
          #pragma unroll
          for (int ni = 0; ni < 4; ++ni) {
            int row0 = m0 + wm + mi * 16 + quad * 4;
            int b = row0 >> 9, sres = row0 & 511;
            int d = wn + ni * 16 + l16;
            us4 pk;
            #pragma unroll
            for (int r = 0; r < 4; ++r) pk[r] = f2bf(acc[mi][ni][r]);
            *(us4*)(Vt + ((size_t)(nt * BATCH + b) * HID + d) * SLEN + sres) = pk;
          }
      }
    }
  }
}

// ---------------------------------------------------------------------------
// Kernel 2: flash attention — R13 (frozen; measured 55.0us, VGPR 60).
// ---------------------------------------------------------------------------
__global__ __launch_bounds__(512, 4) void attn_kernel(
    const unsigned short* __restrict__ Qh,   // (NH, M, 128)
    const unsigned short* __restrict__ Kh,   // (NH, M, 128)
    const unsigned short* __restrict__ Vt,   // (NH, B, 128, S)
    const unsigned int* __restrict__ mbits,  // (B, S, 16)
    unsigned short* __restrict__ ctx)        // (M, 512)
{
  const int lin = blockIdx.x;              // 0..1023
  const int work = (lin & 7) * 128 + (lin >> 3);
  const int qt = work & 3;
  const int h  = (work >> 2) & 3;
  const int b  = work >> 4;

  const int t = threadIdx.x;
  const int lane = t & 63;
  const int w = t >> 6;                    // 0..7
  const int quad = lane >> 4;
  const int l16 = lane & 15;

  __shared__ __align__(16) unsigned short Kld[2][64 * 136];   // 34816 B
  __shared__ __align__(16) unsigned short Vtld[2][128 * 72];  // 36864 B

  const int q0 = qt * 128;
  const size_t rowbase = (size_t)b * SLEN;
  const unsigned short* kbase0 = Kh + ((size_t)h * MTOT + rowbase) * HID;
  const unsigned short* vbase  = Vt + (size_t)(h * BATCH + b) * HID * SLEN;
  const unsigned int* mrow = mbits + (size_t)b * SLEN * 16;

  const int k_key = t >> 4, k_col = (t & 15) << 3;   // +32 keys at i=1
  const int v_d   = t >> 3, v_cc  = (t & 7) << 3;    // +64 d at i=1

  short8 qa[4];
  {
    const unsigned short* qbase =
        Qh + ((size_t)h * MTOT + rowbase + q0 + w * 16 + l16) * HID + quad * 8;
    #pragma unroll
    for (int kk = 0; kk < 4; ++kk)
      qa[kk] = *(const short8*)(qbase + kk * 32);
  }

  short8 ones;
  #pragma unroll
  for (int j = 0; j < 8; ++j) ones[j] = (short)0x3F80;  // bf16 1.0

  f32x4 oc[8], oc9;
  #pragma unroll
  for (int nd = 0; nd < 8; ++nd) oc[nd] = f32x4{0.f, 0.f, 0.f, 0.f};
  oc9 = f32x4{0.f, 0.f, 0.f, 0.f};

  // per-lane q-row is fixed: one mask base
  const unsigned int* mq = mrow + (size_t)(q0 + w * 16 + l16) * 16;

  // prologue: load chunk 0 -> regs -> buf0; load chunk 1 -> regs; barrier
  u32x4 kreg[2], vreg[2];
  #pragma unroll
  for (int i = 0; i < 2; ++i) {
    kreg[i] = *(const u32x4*)(kbase0 + (size_t)(k_key + i * 32) * HID + k_col);
    vreg[i] = *(const u32x4*)(vbase + (size_t)(v_d + i * 64) * SLEN + v_cc);
  }
  #pragma unroll
  for (int i = 0; i < 2; ++i) {
    *(u32x4*)(Kld[0] + (k_key + i * 32) * 136 + k_col) = kreg[i];
    *(u32x4*)(Vtld[0] + (v_d + i * 64) * 72 + v_cc) = vreg[i];
  }
  #pragma unroll
  for (int i = 0; i < 2; ++i) {
    kreg[i] = *(const u32x4*)(kbase0 + (size_t)(64 + k_key + i * 32) * HID + k_col);
    vreg[i] = *(const u32x4*)(vbase + (size_t)(v_d + i * 64) * SLEN + 64 + v_cc);
  }
  asm volatile("s_waitcnt lgkmcnt(0)" ::: "memory");
  __builtin_amdgcn_s_barrier();

  for (int c0 = 0; c0 < SLEN; c0 += 64) {
    const int p = (c0 >> 6) & 1;
    const unsigned short* Kr = Kld[p];
    const unsigned short* Vr = Vtld[p];

    // stage chunk c+1 (held in regs) into the other buffer; then issue
    // global loads for chunk c+2 (land during compute of c and c+1)
    if (c0 + 64 < SLEN) {
      unsigned short* Kw = Kld[p ^ 1];
      unsigned short* Vw = Vtld[p ^ 1];
      #pragma unroll
      for (int i = 0; i < 2; ++i) {
        *(u32x4*)(Kw + (k_key + i * 32) * 136 + k_col) = kreg[i];
        *(u32x4*)(Vw + (v_d + i * 64) * 72 + v_cc) = vreg[i];
      }
      if (c0 + 128 < SLEN) {
        #pragma unroll
        for (int i = 0; i < 2; ++i) {
          kreg[i] = *(const u32x4*)(kbase0 + (size_t)(c0 + 128 + k_key + i * 32) * HID + k_col);
          vreg[i] = *(const u32x4*)(vbase + (size_t)(v_d + i * 64) * SLEN + c0 + 128 + v_cc);
        }
      }
    }

    // mask bits: 64 keys for this lane's q-row (used after QK^T)
    u32x2 mw = *(const u32x2*)(mq + (c0 >> 5));

    // S^T = (Q K^T)^T via swapped operands: lane l16 = q, regs = keys
    f32x4 sc[4];
    #pragma unroll
    for (int ni = 0; ni < 4; ++ni) sc[ni] = f32x4{0.f, 0.f, 0.f, 0.f};
    __builtin_amdgcn_s_setprio(1);
    #pragma unroll
    for (int kk = 0; kk < 4; ++kk) {
      #pragma unroll
      for (int ni = 0; ni < 4; ++ni) {
        short8 bb = *(const short8*)(Kr + (ni * 16 + l16) * 136 + kk * 32 + quad * 8);
        sc[ni] = __builtin_amdgcn_mfma_f32_16x16x32_bf16(bb, qa[kk], sc[ni], 0, 0, 0);
      }
    }
    __builtin_amdgcn_s_setprio(0);

    // p = mask ? exp2(s) : 0, packed to bf16 pairs in-register
    unsigned int pk[4][2];
    #pragma unroll
    for (int ni = 0; ni < 4; ++ni) {
      unsigned wsel = (ni < 2) ? mw[0] : mw[1];
      float pp[4];
      #pragma unroll
      for (int r = 0; r < 4; ++r) {
        int bit = (ni & 1) * 16 + quad * 4 + r;
        float e = __builtin_amdgcn_exp2f(sc[ni][r]);   // raw v_exp_f32
        pp[r] = ((wsel >> bit) & 1u) ? e : 0.f;
      }
      asm("v_cvt_pk_bf16_f32 %0, %1, %2" : "=v"(pk[ni][0]) : "v"(pp[0]), "v"(pp[1]));
      asm("v_cvt_pk_bf16_f32 %0, %1, %2" : "=v"(pk[ni][1]) : "v"(pp[2]), "v"(pp[3]));
    }

    // O += P @ V ; rowsum += P @ 1 ; P A-frags assembled via permlane swaps
    #pragma unroll
    for (int kb = 0; kb < 2; ++kb) {
      unsigned int c0w = pk[kb * 2][0], c2w = pk[kb * 2 + 1][0];
      asm("v_permlane32_swap_b32 %0, %1" : "+v"(c0w), "+v"(c2w));
      asm("v_permlane16_swap_b32 %0, %1" : "+v"(c0w), "+v"(c2w));
      unsigned int c1w = pk[kb * 2][1], c3w = pk[kb * 2 + 1][1];
      asm("v_permlane32_swap_b32 %0, %1" : "+v"(c1w), "+v"(c3w));
      asm("v_permlane16_swap_b32 %0, %1" : "+v"(c1w), "+v"(c3w));
      short8 a = __builtin_bit_cast(short8, u32x4{c0w, c1w, c2w, c3w});
      __builtin_amdgcn_s_setprio(1);
      #pragma unroll
      for (int nd = 0; nd < 8; ++nd) {
        short8 bv = *(const short8*)(Vr + (nd * 16 + l16) * 72 + kb * 32 + quad * 8);
        oc[nd] = __builtin_amdgcn_mfma_f32_16x16x32_bf16(a, bv, oc[nd], 0, 0, 0);
      }
      oc9 = __builtin_amdgcn_mfma_f32_16x16x32_bf16(a, ones, oc9, 0, 0, 0);
      __builtin_amdgcn_s_setprio(0);
    }

    // one barrier per chunk: own LDS writes visible, then all waves align.
    // vmcnt NOT drained -> c+2 loads stay in flight across the barrier.
    if (c0 + 64 < SLEN) {
      asm volatile("s_waitcnt lgkmcnt(0)" ::: "memory");
      __builtin_amdgcn_s_barrier();
    }
  }

  // D[q][d] epilogue: rcp once per row, multiply
  float rcp[4];
  #pragma unroll
  for (int r = 0; r < 4; ++r) rcp[r] = __builtin_amdgcn_rcpf(oc9[r]);
  #pragma unroll
  for (int nd = 0; nd < 8; ++nd)
    #pragma unroll
    for (int r = 0; r < 4; ++r) {
      float val = oc[nd][r] * rcp[r];
      int row = q0 + w * 16 + quad * 4 + r;
      int col = h * HID + nd * 16 + l16;
      ctx[(rowbase + row) * DPROJ + col] = f2bf(val);
    }
}

// ---------------------------------------------------------------------------
// Kernel 3: output projection + residual + LayerNorm — R14 (frozen).
// ---------------------------------------------------------------------------
__global__ __launch_bounds__(256, 2) void oproj_ln_kernel(
    const unsigned short* __restrict__ ctx,   // (M,512) bf16
    const unsigned short* __restrict__ WoT,   // (128,512) bf16 n-major
    const float* __restrict__ enc,            // (M,128) fp32
    const float* __restrict__ gamma,
    const float* __restrict__ beta,
    float* __restrict__ out)                  // (M,128) fp32
{
  const int m0 = blockIdx.x * 64;
  const int t = threadIdx.x;
  const int lane = t & 63;
  const int w = t >> 6;
  const int quad = lane >> 4;
  const int l16 = lane & 15;

  __shared__ __align__(16) unsigned short Actx[2][64 * 72];   // 18432 B
  __shared__ __align__(16) unsigned short Bw[2][128 * 72];    // 36864 B

  const int a_row = t >> 3, a_col = (t & 7) << 3;   // +32 rows at i=1 (64 rows)
  const int b_row = t >> 3, b_col = (t & 7) << 3;   // +32 rows per i (128 rows)

  f32x4 acc[8];
  #pragma unroll
  for (int ni = 0; ni < 8; ++ni) acc[ni] = f32x4{0.f, 0.f, 0.f, 0.f};

  // prologue: (kc=0) -> regs -> buf0; (kc=1) -> regs; barrier
  u32x4 areg[2], breg[4];
  #pragma unroll
  for (int i = 0; i < 2; ++i)
    areg[i] = *(const u32x4*)(ctx + (size_t)(m0 + a_row + i * 32) * DPROJ + a_col);
  #pragma unroll
  for (int i = 0; i < 4; ++i)
    breg[i] = *(const u32x4*)(WoT + (size_t)(b_row + i * 32) * DPROJ + b_col);
  #pragma unroll
  for (int i = 0; i < 2; ++i)
    *(u32x4*)(Actx[0] + (a_row + i * 32) * 72 + a_col) = areg[i];
  #pragma unroll
  for (int i = 0; i < 4; ++i)
    *(u32x4*)(Bw[0] + (b_row + i * 32) * 72 + b_col) = breg[i];
  #pragma unroll
  for (int i = 0; i < 2; ++i)
    areg[i] = *(const u32x4*)(ctx + (size_t)(m0 + a_row + i * 32) * DPROJ + 64 + a_col);
  #pragma unroll
  for (int i = 0; i < 4; ++i)
    breg[i] = *(const u32x4*)(WoT + (size_t)(b_row + i * 32) * DPROJ + 64 + b_col);
  asm volatile("s_waitcnt lgkmcnt(0)" ::: "memory");
  __builtin_amdgcn_s_barrier();

  #pragma unroll
  for (int it = 0; it < 8; ++it) {
    const int p = it & 1;
    const unsigned short* Ar = Actx[p];
    const unsigned short* Br = Bw[p];
    #pragma unroll
    for (int kk = 0; kk < 2; ++kk) {
      short8 a = *(const short8*)(Ar + (w * 16 + l16) * 72 + kk * 32 + quad * 8);
      #pragma unroll
      for (int ni = 0; ni < 8; ++ni) {
        short8 bb = *(const short8*)(Br + (ni * 16 + l16) * 72 + kk * 32 + quad * 8);
        acc[ni] = __builtin_amdgcn_mfma_f32_16x16x32_bf16(a, bb, acc[ni], 0, 0, 0);
      }
    }
    if (it < 7) {
      unsigned short* Aw2 = Actx[p ^ 1];
      unsigned short* Bw2 = Bw[p ^ 1];
      #pragma unroll
      for (int i = 0; i < 2; ++i)
        *(u32x4*)(Aw2 + (a_row + i * 32) * 72 + a_col) = areg[i];
      #pragma unroll
      for (int i = 0; i < 4; ++i)
        *(u32x4*)(Bw2 + (b_row + i * 32) * 72 + b_col) = breg[i];
      if (it < 6) {
        const int kc2 = (it + 2) * 64;
        #pragma unroll
        for (int i = 0; i < 2; ++i)
          areg[i] = *(const u32x4*)(ctx + (size_t)(m0 + a_row + i * 32) * DPROJ + kc2 + a_col);
        #pragma unroll
        for (int i = 0; i < 4; ++i)
          breg[i] = *(const u32x4*)(WoT + (size_t)(b_row + i * 32) * DPROJ + kc2 + b_col);
      }
      asm volatile("s_waitcnt lgkmcnt(0)" ::: "memory");
      __builtin_amdgcn_s_barrier();
    }
  }

  float g[8], be[8];
  #pragma unroll
  for (int ni = 0; ni < 8; ++ni) {
    g[ni] = gamma[ni * 16 + l16];
    be[ni] = beta[ni * 16 + l16];
  }

  float val[8][4];
  #pragma unroll
  for (int r = 0; r < 4; ++r) {
    int m = m0 + w * 16 + quad * 4 + r;
    const float* erow = enc + (size_t)m * HID;
    float s = 0.f, s2 = 0.f;
    #pragma unroll
    for (int ni = 0; ni < 8; ++ni) {
      float v = acc[ni][r] + erow[ni * 16 + l16];
      val[ni][r] = v;
      s += v;
      s2 += v * v;
    }
    #pragma unroll
    for (int off = 1; off < 16; off <<= 1) {
      s  += __shfl_xor(s, off, 64);
      s2 += __shfl_xor(s2, off, 64);
    }
    float mean = s * (1.f / 128.f);
    float var = s2 * (1.f / 128.f) - mean * mean;
    float rstd = rsqrtf(var + 1e-6f);
    float* orow = out + (size_t)m * HID;
    #pragma unroll
    for (int ni = 0; ni < 8; ++ni)
      orow[ni * 16 + l16] = g[ni] * (val[ni][r] - mean) * rstd + be[ni];
  }
}

// ---------------------------------------------------------------------------
// ws layout (elements):
//   WT   : 3*512*128 shorts        WoT : 128*512 shorts
//   Qh   : 4*M*128 shorts          Kh  : 4*M*128 shorts
//   Vt   : 4*64*128*512 shorts     ctx : M*512 shorts
//   mbits: 64*512*16 u32
// ---------------------------------------------------------------------------
extern "C" void kernel_launch(void* const* d_in, const int* in_sizes, int n_in,
                              void* d_out, int out_size, void* d_ws, size_t ws_size,
                              hipStream_t stream) {
  const float* enc   = (const float*)d_in[0];
  const int*   mask  = (const int*)d_in[1];
  const float* Wq    = (const float*)d_in[2];
  const float* Wk    = (const float*)d_in[3];
  const float* Wv    = (const float*)d_in[4];
  const float* Wo    = (const float*)d_in[5];
  const float* gamma = (const float*)d_in[6];
  const float* beta  = (const float*)d_in[7];
  float* out = (float*)d_out;

  unsigned short* WT  = (unsigned short*)d_ws;
  unsigned short* WoT = WT + (size_t)3 * DPROJ * HID;
  unsigned short* Qh  = WoT + (size_t)HID * DPROJ;
  unsigned short* Kh  = Qh + (size_t)NHEAD * MTOT * HID;
  unsigned short* Vt  = Kh + (size_t)NHEAD * MTOT * HID;
  unsigned short* ctx = Vt + (size_t)NHEAD * MTOT * HID;
  unsigned int* mbits = (unsigned int*)(ctx + (size_t)MTOT * DPROJ);

  prep_kernel<<<2048, 256, 0, stream>>>(Wq, Wk, Wv, Wo, mask, WT, WoT, mbits);
  qkv_kernel<<<1024, 256, 0, stream>>>(enc, WT, Qh, Kh, Vt);
  attn_kernel<<<1024, 512, 0, stream>>>(Qh, Kh, Vt, mbits, ctx);
  oproj_ln_kernel<<<MTOT / 64, 256, 0, stream>>>(ctx, WoT, enc, gamma, beta, out);
}